// Round 1
// baseline (453.123 us; speedup 1.0000x reference)
//
#include <hip/hip_runtime.h>

// Element-wise 16-step spiking recurrence.
//   v = x; z = 0; out = 0
//   for t in 0..15: v -= z*h[t]; z = (v - T[t])/(|v|+1) > 0; out += z*d[t]
// Since |v|+1 > 0, the spike condition is exactly (v > T[t]) -> no divide.
// z in {0,1} so fmaf(-z,h,v) computes exactly v or v-h (same rounding as ref).

#define ELEMS_PER_VEC 4

__global__ __launch_bounds__(256) void spike_recurrence_kernel(
    const float* __restrict__ x,
    const float* __restrict__ h,
    const float* __restrict__ d,
    const float* __restrict__ T,
    float* __restrict__ out,
    int n4, int n)
{
    // Wave-uniform constant loads -> compiler emits scalar loads into SGPRs.
    float hh[16], dd[16], tt[16];
#pragma unroll
    for (int t = 0; t < 16; ++t) {
        hh[t] = h[t];
        dd[t] = d[t];
        tt[t] = T[t];
    }

    const float4* __restrict__ x4 = reinterpret_cast<const float4*>(x);
    float4* __restrict__ o4 = reinterpret_cast<float4*>(out);

    int tid = blockIdx.x * blockDim.x + threadIdx.x;
    int stride = gridDim.x * blockDim.x;

    for (int i = tid; i < n4; i += stride) {
        float4 xv = x4[i];
        float v[4] = {xv.x, xv.y, xv.z, xv.w};
        float z[4] = {0.f, 0.f, 0.f, 0.f};
        float o[4] = {0.f, 0.f, 0.f, 0.f};
#pragma unroll
        for (int t = 0; t < 16; ++t) {
#pragma unroll
            for (int j = 0; j < 4; ++j) {
                v[j] = fmaf(-z[j], hh[t], v[j]);      // v -= z*h[t] (exact: z in {0,1})
                z[j] = (v[j] > tt[t]) ? 1.0f : 0.0f;  // sign((v-T)/(|v|+1)) == sign(v-T)
                o[j] = fmaf(z[j], dd[t], o[j]);       // out += z*d[t]
            }
        }
        o4[i] = make_float4(o[0], o[1], o[2], o[3]);
    }

    // Scalar tail (n not divisible by 4) — not hit for this problem (N = 2^26).
    int tail_start = n4 * ELEMS_PER_VEC;
    for (int i = tail_start + tid; i < n; i += stride) {
        float v = x[i], z = 0.f, o = 0.f;
#pragma unroll
        for (int t = 0; t < 16; ++t) {
            v = fmaf(-z, hh[t], v);
            z = (v > tt[t]) ? 1.0f : 0.0f;
            o = fmaf(z, dd[t], o);
        }
        out[i] = o;
    }
}

extern "C" void kernel_launch(void* const* d_in, const int* in_sizes, int n_in,
                              void* d_out, int out_size, void* d_ws, size_t ws_size,
                              hipStream_t stream) {
    const float* x = (const float*)d_in[0];
    const float* h = (const float*)d_in[1];
    const float* d = (const float*)d_in[2];
    const float* T = (const float*)d_in[3];
    float* out = (float*)d_out;

    int n = in_sizes[0];          // 4*4096*4096 = 67,108,864
    int n4 = n / ELEMS_PER_VEC;   // 16,777,216 float4 groups

    // 16384 blocks x 256 threads -> 4 float4 (16 elems) per thread via grid-stride.
    int block = 256;
    int grid = 16384;
    spike_recurrence_kernel<<<grid, block, 0, stream>>>(x, h, d, T, out, n4, n);
}

// Round 3
// 444.158 us; speedup vs baseline: 1.0202x; 1.0202x over previous
//
#include <hip/hip_runtime.h>

// Element-wise 16-step spiking recurrence.
//   v = x; z = 0; out = 0
//   for t in 0..15: v -= z*h[t]; z = (v - T[t])/(|v|+1) > 0; out += z*d[t]
// |v|+1 > 0  =>  spike condition is exactly (v > T[t]) -> no divide.
// z in {0,1} so fmaf(-z,h,v) rounds identically to the reference's v - z*h.
//
// Streaming config: one float4 per thread, 65536 blocks x 256 threads covers
// n4 = 16.7M float4 groups exactly; every wave issues its 16B/lane load at
// launch (max bytes in flight). x and out are both touched exactly once ->
// nontemporal load/store. Native clang vector type (not HIP float4 struct)
// because __builtin_nontemporal_* requires a real vector type.

typedef float floatv4 __attribute__((ext_vector_type(4)));

__global__ __launch_bounds__(256) void spike_recurrence_kernel(
    const float* __restrict__ x,
    const float* __restrict__ h,
    const float* __restrict__ d,
    const float* __restrict__ T,
    float* __restrict__ out,
    int n4)
{
    int i = blockIdx.x * blockDim.x + threadIdx.x;
    if (i >= n4) return;

    // Wave-uniform constant loads -> scalar loads into SGPRs.
    float hh[16], dd[16], tt[16];
#pragma unroll
    for (int t = 0; t < 16; ++t) {
        hh[t] = h[t];
        dd[t] = d[t];
        tt[t] = T[t];
    }

    const floatv4* __restrict__ x4 = reinterpret_cast<const floatv4*>(x);
    floatv4* __restrict__ o4 = reinterpret_cast<floatv4*>(out);

    floatv4 xv = __builtin_nontemporal_load(&x4[i]);   // streamed, read once
    float v[4] = {xv.x, xv.y, xv.z, xv.w};
    float z[4] = {0.f, 0.f, 0.f, 0.f};
    float o[4] = {0.f, 0.f, 0.f, 0.f};
#pragma unroll
    for (int t = 0; t < 16; ++t) {
#pragma unroll
        for (int j = 0; j < 4; ++j) {
            v[j] = fmaf(-z[j], hh[t], v[j]);      // v -= z*h[t] (exact: z in {0,1})
            z[j] = (v[j] > tt[t]) ? 1.0f : 0.0f;  // sign((v-T)/(|v|+1)) == sign(v-T)
            o[j] = fmaf(z[j], dd[t], o[j]);       // out += z*d[t]
        }
    }
    floatv4 ov = {o[0], o[1], o[2], o[3]};
    __builtin_nontemporal_store(ov, &o4[i]);      // streaming store, no re-read
}

extern "C" void kernel_launch(void* const* d_in, const int* in_sizes, int n_in,
                              void* d_out, int out_size, void* d_ws, size_t ws_size,
                              hipStream_t stream) {
    const float* x = (const float*)d_in[0];
    const float* h = (const float*)d_in[1];
    const float* d = (const float*)d_in[2];
    const float* T = (const float*)d_in[3];
    float* out = (float*)d_out;

    int n = in_sizes[0];          // 4*4096*4096 = 67,108,864 (divisible by 4)
    int n4 = n / 4;               // 16,777,216 float4 groups

    int block = 256;
    int grid = (n4 + block - 1) / block;   // 65536 blocks, exact cover
    spike_recurrence_kernel<<<grid, block, 0, stream>>>(x, h, d, T, out, n4);
}